// Round 6
// baseline (198.463 us; speedup 1.0000x reference)
//
#include <hip/hip_runtime.h>

#define NLVL 16
#define LOGT 19
#define TMASK ((1u << LOGT) - 1u)
#define SCALE 4096.0f
#define INV_SCALE (1.0f / 4096.0f)
#define NFRAG 22

// compact dense grids for levels 0..3 (res 16,20,25,32)
#define NCG 4
#define CG_TOTAL 67687          // 17^3 + 21^3 + 26^3 + 33^3
#define CG_TOTAL_PAD 67700      // 16B-aligned-per-level + vec-load slack
#define CG_BLOCKS 265           // ceil(67687/256)

typedef _Float16 half_t;
typedef half_t half8 __attribute__((ext_vector_type(8)));
typedef half_t half4 __attribute__((ext_vector_type(4)));
typedef half_t half2v __attribute__((ext_vector_type(2)));
typedef float  float4v __attribute__((ext_vector_type(4)));
typedef unsigned int uint4v __attribute__((ext_vector_type(4)));

__device__ __constant__ float RES_C[NLVL] = {16.f, 20.f, 25.f, 32.f, 40.f, 50.f, 64.f, 80.f,
                                             101.f, 128.f, 161.f, 203.f, 256.f, 322.f, 406.f, 512.f};
__device__ __constant__ int CG_SIZE[NCG] = {4913, 9261, 17576, 35937};
__device__ __constant__ int CG_OFF[NCG]  = {0, 4916, 14180, 31760};   // 4-uint aligned
__device__ __constant__ int CG_R1[NCG]   = {17, 21, 26, 33};          // res+1

__device__ __forceinline__ float4v mfma16(half8 a, half8 b, float4v c) {
    return __builtin_amdgcn_mfma_f32_16x16x32_f16(a, b, c, 0, 0, 0);
}

// ---------------- Kernel A: 12 hashed levels (4..15), 1.5 levels per XCD ----------------
// Phase A (b < 8*bpl): level 4+(b&7) pinned 1:1 to XCD b%8.
// Phase B (next 4*bpl): levels 12..15 each split across an XCD PAIR (b2&7 -> {0,1}=12,
// {2,3}=13, {4,5}=14, {6,7}=15); each XCD's private L2 caches the full 4MB table.
// Per-XCD random line-requests: 2.36M -> 1.77M (x0.75) => ~67-75us at the measured
// ~0.69 line-req/cy/channel wall.
// Tail blocks: 22 weight-prep frags + 265 compact-grid-build blocks (levels 0..3),
// consumed by the staged kernel in the NEXT dispatch (ordering safe).
__global__ __launch_bounds__(256, 8) void nerf_encode_h12(
    const float* __restrict__ coords,
    const float2* __restrict__ tab,
    const float* __restrict__ w_in, const float* __restrict__ w_h0,
    const float* __restrict__ w_h1, const float* __restrict__ w_out,
    half8* __restrict__ frags,
    unsigned* __restrict__ compact,
    half_t* __restrict__ encT, int npts)
{
    const int bpl   = npts >> 8;
    const int nHash = 12 * bpl;
    const int b     = blockIdx.x;

    if (b >= nHash) {                      // ---- tail: weight-prep + compact build ----
        const int tb = b - nHash;
        if (tb < NFRAG) {
            if (threadIdx.x < 64) {
                const int frag = tb;
                const int lane = threadIdx.x;
                const int m    = lane & 15;
                const int quad = lane >> 4;
                const float* W; int ncol, row, col;
                if (frag < 4)       { W = w_in;  ncol = 32; row = frag * 16 + m;      col = quad * 8; }
                else if (frag < 12) { const int f = frag - 4;
                                      W = w_h0;  ncol = 64; row = (f >> 1) * 16 + m;  col = (f & 1) * 32 + quad * 8; }
                else if (frag < 20) { const int f = frag - 12;
                                      W = w_h1;  ncol = 64; row = (f >> 1) * 16 + m;  col = (f & 1) * 32 + quad * 8; }
                else                { const int f = frag - 20;
                                      W = w_out; ncol = 64; row = m;                  col = f * 32 + quad * 8; }
                const float* p = W + row * ncol + col;
                half8 r;
                #pragma unroll
                for (int j = 0; j < 8; ++j) r[j] = (half_t)p[j];
                frags[frag * 64 + lane] = r;
            }
        } else {
            const int vid = (tb - NFRAG) * 256 + (int)threadIdx.x;
            if (vid < CG_TOTAL) {
                const int l = (vid >= 31750) ? 3 : (vid >= 14174) ? 2 : (vid >= 4913) ? 1 : 0;
                const int voff = (l == 3) ? 31750 : (l == 2) ? 14174 : (l == 1) ? 4913 : 0;
                const int v  = vid - voff;
                const int r1 = CG_R1[l];
                const int z  = v % r1;
                const int r2 = v / r1;
                const int y  = r2 % r1;
                const int x  = r2 / r1;
                const unsigned idx = ((unsigned)x
                                    ^ ((unsigned)y * 2654435761u)
                                    ^ ((unsigned)z * 805459861u)) & TMASK;
                const float2 tv = tab[(((unsigned)l) << LOGT) + idx];
                half2v h; h[0] = (half_t)tv.x; h[1] = (half_t)tv.y;   // fp16 round-trip exact
                compact[CG_OFF[l] + v] = __builtin_bit_cast(unsigned, h);
            }
        }
        return;
    }

    // ---- hashed-level mapping ----
    int l, pb;
    const int phaseA = 8 * bpl;
    if (b < phaseA) { l = 4 + (b & 7); pb = b >> 3; }
    else {
        const int b2 = b - phaseA;                 // [0, 4*bpl)
        l  = 12 + ((b2 & 7) >> 1);
        pb = ((b2 >> 3) << 1) + (b2 & 1);          // bijection onto [0, bpl)
    }

    const int side = threadIdx.x & 1;              // 0 = floor-x, 1 = ceil-x
    const int base = pb * 256 + (threadIdx.x >> 1);
    const int p0 = base, p1 = base + 128;

    const float r = RES_C[l];
    const float2* __restrict__ bp = tab + (((unsigned)l) << LOGT);

    const float ax = coords[p0 * 3 + 0] * r, ay = coords[p0 * 3 + 1] * r, az = coords[p0 * 3 + 2] * r;
    const float afx = floorf(ax), afy = floorf(ay), afz = floorf(az);
    const float agx = ceilf(ax),  agy = ceilf(ay),  agz = ceilf(az);
    const unsigned ahx = side ? (unsigned)(int)agx : (unsigned)(int)afx;
    const float    awx = side ? (ax - afx) : (agx - ax);
    const unsigned ahfy = (unsigned)(int)afy * 2654435761u;
    const unsigned ahgy = (unsigned)(int)agy * 2654435761u;
    const unsigned ahfz = (unsigned)(int)afz * 805459861u;
    const unsigned ahgz = (unsigned)(int)agz * 805459861u;
    const float aty = ay - afy, atz = az - afz, auy = agy - ay, auz = agz - az;

    const float bx = coords[p1 * 3 + 0] * r, by = coords[p1 * 3 + 1] * r, bz = coords[p1 * 3 + 2] * r;
    const float bfx = floorf(bx), bfy = floorf(by), bfz = floorf(bz);
    const float bgx = ceilf(bx),  bgy = ceilf(by),  bgz = ceilf(bz);
    const unsigned bhx = side ? (unsigned)(int)bgx : (unsigned)(int)bfx;
    const float    bwx = side ? (bx - bfx) : (bgx - bx);
    const unsigned bhfy = (unsigned)(int)bfy * 2654435761u;
    const unsigned bhgy = (unsigned)(int)bgy * 2654435761u;
    const unsigned bhfz = (unsigned)(int)bfz * 805459861u;
    const unsigned bhgz = (unsigned)(int)bgz * 805459861u;
    const float bty = by - bfy, btz = bz - bfz, buy = bgy - by, buz = bgz - bz;

    const float2 a0 = bp[(ahx ^ ahfy ^ ahfz) & TMASK];
    const float2 a1 = bp[(ahx ^ ahfy ^ ahgz) & TMASK];
    const float2 a2 = bp[(ahx ^ ahgy ^ ahfz) & TMASK];
    const float2 a3 = bp[(ahx ^ ahgy ^ ahgz) & TMASK];
    const float2 b0 = bp[(bhx ^ bhfy ^ bhfz) & TMASK];
    const float2 b1 = bp[(bhx ^ bhfy ^ bhgz) & TMASK];
    const float2 b2 = bp[(bhx ^ bhgy ^ bhfz) & TMASK];
    const float2 b3 = bp[(bhx ^ bhgy ^ bhgz) & TMASK];

    const float aw0 = awx * auy * auz, aw1 = awx * auy * atz;
    const float aw2 = awx * aty * auz, aw3 = awx * aty * atz;
    const float bw0 = bwx * buy * buz, bw1 = bwx * buy * btz;
    const float bw2 = bwx * bty * buz, bw3 = bwx * bty * btz;

    float ae0 = aw0 * a0.x + aw1 * a1.x + aw2 * a2.x + aw3 * a3.x;
    float ae1 = aw0 * a0.y + aw1 * a1.y + aw2 * a2.y + aw3 * a3.y;
    float be0 = bw0 * b0.x + bw1 * b1.x + bw2 * b2.x + bw3 * b3.x;
    float be1 = bw0 * b0.y + bw1 * b1.y + bw2 * b2.y + bw3 * b3.y;

    ae0 += __shfl_xor(ae0, 1, 64);
    ae1 += __shfl_xor(ae1, 1, 64);
    be0 += __shfl_xor(be0, 1, 64);
    be1 += __shfl_xor(be1, 1, 64);

    if (side == 0) {
        half2v h0; h0[0] = (half_t)(ae0 * SCALE); h0[1] = (half_t)(ae1 * SCALE);
        half2v h1; h1[0] = (half_t)(be0 * SCALE); h1[1] = (half_t)(be1 * SCALE);
        *reinterpret_cast<half2v*>(&encT[((size_t)l * npts + p0) * 2]) = h0;
        *reinterpret_cast<half2v*>(&encT[((size_t)l * npts + p1) * 2]) = h1;
    }
}

// ---------------- Kernel A2: levels 0..3 from LDS-staged compact dense grids ----------------
// Block s: level = s>>6, point-chunk = s&63 (4096 pts each; geometry requires
// npts == 262144 exactly -- guarded in the launcher). Stage (res+1)^3 half2 entries
// (19.7..143.7 KB; < 160 KB HW LDS limit, 128-160 KB precedent on gfx950) sequentially,
// then all 8 corner reads per point-level are LDS reads -- zero random L2 requests
// for these 4 levels. Arithmetic mirrors the hash path exactly (floor-x group +
// ceil-x group, then add; left-assoc 4-term dot) so outputs match bitwise up to
// fma-contraction noise already within tolerance.
__global__ __launch_bounds__(256, 1) void nerf_encode_stage(
    const float* __restrict__ coords,
    const unsigned* __restrict__ compact,
    half_t* __restrict__ encT, int npts)
{
    __shared__ unsigned sgrid[35940];              // 143,760 B (level-3 grid + vec slack)

    const int s     = blockIdx.x;
    const int l     = s >> 6;
    const int chunk = s & 63;
    const int t     = threadIdx.x;

    const int sz = CG_SIZE[l];
    const unsigned* __restrict__ src = compact + CG_OFF[l];
    const int n4 = (sz + 3) >> 2;
    for (int i = t; i < n4; i += 256) {
        const uint4v v = *reinterpret_cast<const uint4v*>(src + i * 4);
        *reinterpret_cast<uint4v*>(&sgrid[i * 4]) = v;
    }
    __syncthreads();

    const float r  = RES_C[l];
    const int   r1 = CG_R1[l];
    const int   p0 = chunk * 4096 + t;

    #pragma unroll 4
    for (int k = 0; k < 16; ++k) {
        const int p = p0 + k * 256;
        const float cx = coords[p * 3 + 0], cy = coords[p * 3 + 1], cz = coords[p * 3 + 2];
        const float sx = cx * r, sy = cy * r, szf = cz * r;
        const float fx = floorf(sx), fy = floorf(sy), fz = floorf(szf);
        const float gx = ceilf(sx),  gy = ceilf(sy),  gz = ceilf(szf);
        const int ixf = (int)fx, iyf = (int)fy, izf = (int)fz;
        const int ixg = (int)gx, iyg = (int)gy, izg = (int)gz;

        const float wxf = gx - sx, wxc = sx - fx;
        const float uy = gy - sy, ty = sy - fy;
        const float uz = gz - szf, tz = szf - fz;

        const int bf = ixf * r1, bg = ixg * r1;
        const int rf = (bf + iyf) * r1, rF = (bf + iyg) * r1;
        const int rg = (bg + iyf) * r1, rG = (bg + iyg) * r1;

        const half2v c0 = __builtin_bit_cast(half2v, sgrid[rf + izf]);
        const half2v c1 = __builtin_bit_cast(half2v, sgrid[rf + izg]);
        const half2v c2 = __builtin_bit_cast(half2v, sgrid[rF + izf]);
        const half2v c3 = __builtin_bit_cast(half2v, sgrid[rF + izg]);
        const half2v c4 = __builtin_bit_cast(half2v, sgrid[rg + izf]);
        const half2v c5 = __builtin_bit_cast(half2v, sgrid[rg + izg]);
        const half2v c6 = __builtin_bit_cast(half2v, sgrid[rG + izf]);
        const half2v c7 = __builtin_bit_cast(half2v, sgrid[rG + izg]);

        const float w0 = wxf * uy * uz, w1 = wxf * uy * tz;
        const float w2 = wxf * ty * uz, w3 = wxf * ty * tz;
        const float w4 = wxc * uy * uz, w5 = wxc * uy * tz;
        const float w6 = wxc * ty * uz, w7 = wxc * ty * tz;

        float e0f = w0 * (float)c0[0] + w1 * (float)c1[0] + w2 * (float)c2[0] + w3 * (float)c3[0];
        float e1f = w0 * (float)c0[1] + w1 * (float)c1[1] + w2 * (float)c2[1] + w3 * (float)c3[1];
        float e0c = w4 * (float)c4[0] + w5 * (float)c5[0] + w6 * (float)c6[0] + w7 * (float)c7[0];
        float e1c = w4 * (float)c4[1] + w5 * (float)c5[1] + w6 * (float)c6[1] + w7 * (float)c7[1];
        const float e0 = e0f + e0c;
        const float e1 = e1f + e1c;

        half2v h; h[0] = (half_t)(e0 * SCALE); h[1] = (half_t)(e1 * SCALE);
        *reinterpret_cast<half2v*>(&encT[((size_t)l * npts + p) * 2]) = h;
    }
}

// ---------------- In-register layer transition (proven correct: absmax unchanged R1-R4) ----------------
__device__ __forceinline__ unsigned pack_relu2(float x, float y) {
    half2v h;
    h[0] = (half_t)fmaxf(x, 0.f);
    h[1] = (half_t)fmaxf(y, 0.f);
    return __builtin_bit_cast(unsigned, h);
}

__device__ __forceinline__ void xpose_relu(const float4v acc[4], int lane,
                                           half8& b0, half8& b1) {
    unsigned X[4], Y[4];
    X[0] = pack_relu2(acc[0][0], acc[0][1]);
    X[1] = pack_relu2(acc[0][2], acc[0][3]);
    X[2] = pack_relu2(acc[2][0], acc[2][1]);
    X[3] = pack_relu2(acc[2][2], acc[2][3]);
    Y[0] = pack_relu2(acc[1][0], acc[1][1]);
    Y[1] = pack_relu2(acc[1][2], acc[1][3]);
    Y[2] = pack_relu2(acc[3][0], acc[3][1]);
    Y[3] = pack_relu2(acc[3][2], acc[3][3]);
    const bool lo = (lane & 32) == 0;
    const bool ev = (lane & 16) == 0;
    uint4v u0, u1;
    #pragma unroll
    for (int j = 0; j < 4; ++j) {
        const unsigned s1 = lo ? Y[j] : X[j];
        const unsigned t1 = __shfl_xor(s1, 32, 64);
        const unsigned A1 = lo ? X[j] : t1;
        const unsigned B1 = lo ? t1 : Y[j];
        const unsigned s2 = ev ? B1 : A1;
        const unsigned t2 = __shfl_xor(s2, 16, 64);
        const unsigned a2 = ev ? A1 : t2;
        const unsigned b2 = ev ? t2 : B1;
        if (j < 2) { u0[j] = a2; u0[2 + j] = b2; }
        else       { u1[j - 2] = a2; u1[j] = b2; }
    }
    b0 = __builtin_bit_cast(half8, u0);
    b1 = __builtin_bit_cast(half8, u1);
}

// ---------------- Kernel B: register-transpose MLP (measured ~11us; unchanged) ----------------
__global__ __launch_bounds__(256, 3) void nerf_mlp7(
    const half_t* __restrict__ encT,
    const half8* __restrict__ frags,
    const float* __restrict__ b_in, const float* __restrict__ b_h0,
    const float* __restrict__ b_h1, const float* __restrict__ b_out,
    float* __restrict__ out, int npts)
{
    const int t    = threadIdx.x;
    const int lane = t & 63;
    const int wv   = t >> 6;
    const int m    = lane & 15;
    const int quad = lane >> 4;
    const size_t pbase = (size_t)blockIdx.x * 256 + (size_t)wv * 64;

    half8 be[4];
    #pragma unroll
    for (int T = 0; T < 4; ++T) {
        #pragma unroll
        for (int d = 0; d < 4; ++d) {
            const int L = quad * 4 + d;
            const half2v v = *reinterpret_cast<const half2v*>(
                &encT[((size_t)L * npts + pbase + T * 16 + m) * 2]);
            be[T][d * 2 + 0] = v[0];
            be[T][d * 2 + 1] = v[1];
        }
    }

    half8 bf0[4], bf1[4];

    // ---- layer 1: 32 -> 64 ----
    {
        half8 w[4];
        #pragma unroll
        for (int f = 0; f < 4; ++f) w[f] = frags[(0 + f) * 64 + lane];
        float4v cin[4];
        #pragma unroll
        for (int mt = 0; mt < 4; ++mt)
            cin[mt] = (*reinterpret_cast<const float4v*>(b_in + mt * 16 + quad * 4)) * SCALE;
        #pragma unroll
        for (int T = 0; T < 4; ++T) {
            float4v acc[4];
            #pragma unroll
            for (int mt = 0; mt < 4; ++mt) acc[mt] = mfma16(w[mt], be[T], cin[mt]);
            xpose_relu(acc, lane, bf0[T], bf1[T]);
        }
    }
    // ---- layer 2: 64 -> 64 ----
    {
        half8 w[8];
        #pragma unroll
        for (int f = 0; f < 8; ++f) w[f] = frags[(4 + f) * 64 + lane];
        float4v cin[4];
        #pragma unroll
        for (int mt = 0; mt < 4; ++mt)
            cin[mt] = (*reinterpret_cast<const float4v*>(b_h0 + mt * 16 + quad * 4)) * SCALE;
        #pragma unroll
        for (int T = 0; T < 4; ++T) {
            float4v acc[4];
            #pragma unroll
            for (int mt = 0; mt < 4; ++mt) {
                acc[mt] = mfma16(w[mt * 2 + 0], bf0[T], cin[mt]);
                acc[mt] = mfma16(w[mt * 2 + 1], bf1[T], acc[mt]);
            }
            xpose_relu(acc, lane, bf0[T], bf1[T]);
        }
    }
    // ---- layer 3: 64 -> 64 ----
    {
        half8 w[8];
        #pragma unroll
        for (int f = 0; f < 8; ++f) w[f] = frags[(12 + f) * 64 + lane];
        float4v cin[4];
        #pragma unroll
        for (int mt = 0; mt < 4; ++mt)
            cin[mt] = (*reinterpret_cast<const float4v*>(b_h1 + mt * 16 + quad * 4)) * SCALE;
        #pragma unroll
        for (int T = 0; T < 4; ++T) {
            float4v acc[4];
            #pragma unroll
            for (int mt = 0; mt < 4; ++mt) {
                acc[mt] = mfma16(w[mt * 2 + 0], bf0[T], cin[mt]);
                acc[mt] = mfma16(w[mt * 2 + 1], bf1[T], acc[mt]);
            }
            xpose_relu(acc, lane, bf0[T], bf1[T]);
        }
    }
    // ---- layer 4: 64 -> 16, coalesced float4 store ----
    {
        const half8 w0 = frags[20 * 64 + lane];
        const half8 w1 = frags[21 * 64 + lane];
        const float4v b4 = *reinterpret_cast<const float4v*>(b_out + quad * 4);
        const float4v zero = {0.f, 0.f, 0.f, 0.f};
        #pragma unroll
        for (int T = 0; T < 4; ++T) {
            float4v acc = mfma16(w0, bf0[T], zero);
            acc         = mfma16(w1, bf1[T], acc);
            float4v res;
            #pragma unroll
            for (int r = 0; r < 4; ++r) res[r] = fmaf(acc[r], INV_SCALE, b4[r]);
            *reinterpret_cast<float4v*>(out + (pbase + T * 16 + m) * 16 + quad * 4) = res;
        }
    }
}

// ---------------- Fallback: fused kernel (used only if ws too small; unchanged) ----------------
__global__ __launch_bounds__(256, 2) void nerf_fused(
    const float* __restrict__ coords,
    const float2* __restrict__ tab,
    const float* __restrict__ w_in, const float* __restrict__ b_in,
    const float* __restrict__ w_h0, const float* __restrict__ b_h0,
    const float* __restrict__ w_h1, const float* __restrict__ b_h1,
    const float* __restrict__ w_out, const float* __restrict__ b_out,
    float* __restrict__ out, int npts)
{
    __shared__ half_t encS[256 * 40];
    __shared__ half_t actS[4][2][32 * 64];

    const int t    = threadIdx.x;
    const int lane = t & 63;
    const int wv   = t >> 6;
    const int m    = lane & 15;
    const int quad = lane >> 4;
    const int pt = blockIdx.x * 256 + t;

    {
        const float cx = coords[pt * 3 + 0];
        const float cy = coords[pt * 3 + 1];
        const float cz = coords[pt * 3 + 2];
        float enc[32];
        #pragma unroll
        for (int l = 0; l < NLVL; ++l) {
            const float r = RES_C[l];
            const float sx = cx * r, sy = cy * r, sz = cz * r;
            const float fx = floorf(sx), fy = floorf(sy), fz = floorf(sz);
            const float gx = ceilf(sx),  gy = ceilf(sy),  gz = ceilf(sz);
            const unsigned hfx = (unsigned)(int)fx;
            const unsigned hgx = (unsigned)(int)gx;
            const unsigned hfy = (unsigned)(int)fy * 2654435761u;
            const unsigned hgy = (unsigned)(int)gy * 2654435761u;
            const unsigned hfz = (unsigned)(int)fz * 805459861u;
            const unsigned hgz = (unsigned)(int)gz * 805459861u;
            const float tx = sx - fx, ty = sy - fy, tz = sz - fz;
            const float ux = gx - sx, uy = gy - sy, uz = gz - sz;
            const unsigned lbase = ((unsigned)l) << LOGT;
            float e0 = 0.f, e1 = 0.f;
            #pragma unroll
            for (int o = 0; o < 8; ++o) {
                const unsigned h = ((o & 4) ? hgx : hfx)
                                 ^ ((o & 2) ? hgy : hfy)
                                 ^ ((o & 1) ? hgz : hfz);
                const unsigned idx = h & TMASK;
                const float w = (((o & 4) ? tx : ux)
                              *  ((o & 2) ? ty : uy))
                              *  ((o & 1) ? tz : uz);
                const float2 fv = tab[lbase + idx];
                e0 = fmaf(w, fv.x, e0);
                e1 = fmaf(w, fv.y, e1);
            }
            enc[2 * l + 0] = e0;
            enc[2 * l + 1] = e1;
        }
        #pragma unroll
        for (int c = 0; c < 4; ++c) {
            half8 h8;
            #pragma unroll
            for (int j = 0; j < 8; ++j) h8[j] = (half_t)(enc[c * 8 + j] * SCALE);
            *reinterpret_cast<half8*>(&encS[t * 40 + c * 8]) = h8;
        }
    }

    auto loadA = [&](const float* __restrict__ W, int ncol, int row, int col) -> half8 {
        const float* p = W + row * ncol + col;
        const float4v lo = *reinterpret_cast<const float4v*>(p);
        const float4v hi = *reinterpret_cast<const float4v*>(p + 4);
        half8 r;
        r[0] = (half_t)lo[0]; r[1] = (half_t)lo[1]; r[2] = (half_t)lo[2]; r[3] = (half_t)lo[3];
        r[4] = (half_t)hi[0]; r[5] = (half_t)hi[1]; r[6] = (half_t)hi[2]; r[7] = (half_t)hi[3];
        return r;
    };

    half8 aL1[4], aL2[8], aL3[8], aL4[2];
    #pragma unroll
    for (int mt = 0; mt < 4; ++mt) aL1[mt] = loadA(w_in, 32, mt * 16 + m, quad * 8);
    #pragma unroll
    for (int mt = 0; mt < 4; ++mt) {
        aL2[mt * 2 + 0] = loadA(w_h0, 64, mt * 16 + m, 0 * 32 + quad * 8);
        aL2[mt * 2 + 1] = loadA(w_h0, 64, mt * 16 + m, 1 * 32 + quad * 8);
        aL3[mt * 2 + 0] = loadA(w_h1, 64, mt * 16 + m, 0 * 32 + quad * 8);
        aL3[mt * 2 + 1] = loadA(w_h1, 64, mt * 16 + m, 1 * 32 + quad * 8);
    }
    aL4[0] = loadA(w_out, 64, m, 0 * 32 + quad * 8);
    aL4[1] = loadA(w_out, 64, m, 1 * 32 + quad * 8);

    float4v bL1[4], bL2[4], bL3[4], bL4;
    #pragma unroll
    for (int mt = 0; mt < 4; ++mt) {
        bL1[mt] = *reinterpret_cast<const float4v*>(b_in + mt * 16 + quad * 4);
        bL2[mt] = *reinterpret_cast<const float4v*>(b_h0 + mt * 16 + quad * 4);
        bL3[mt] = *reinterpret_cast<const float4v*>(b_h1 + mt * 16 + quad * 4);
    }
    bL4 = *reinterpret_cast<const float4v*>(b_out + quad * 4);

    half_t* const ping = &actS[wv][0][0];
    half_t* const pong = &actS[wv][1][0];
    const float4v zero = {0.f, 0.f, 0.f, 0.f};

    auto storeTile = [&](half_t* buf, int lp, int mt, float4v acc, float4v bias) {
        half4 h4;
        #pragma unroll
        for (int r = 0; r < 4; ++r)
            h4[r] = (half_t)fmaxf(fmaf(bias[r], SCALE, acc[r]), 0.f);
        const int c16  = mt * 2 + (quad >> 1);
        const int phys = c16 ^ (lp & 7);
        *reinterpret_cast<half4*>(&buf[lp * 64 + phys * 8 + (quad & 1) * 4]) = h4;
    };
    auto loadB = [&](half_t* buf, int lp, int h) -> half8 {
        const int phys = (h * 4 + quad) ^ (lp & 7);
        return *reinterpret_cast<const half8*>(&buf[lp * 64 + phys * 8]);
    };

    for (int g = 0; g < 2; ++g) {
        #pragma unroll
        for (int nt = 0; nt < 2; ++nt) {
            const int lp   = nt * 16 + m;
            const int prow = wv * 64 + g * 32 + lp;
            const half8 bfr = *reinterpret_cast<const half8*>(&encS[prow * 40 + quad * 8]);
            #pragma unroll
            for (int mt = 0; mt < 4; ++mt) {
                float4v acc = mfma16(aL1[mt], bfr, zero);
                storeTile(ping, lp, mt, acc, bL1[mt]);
            }
            {
                const half8 p0 = loadB(ping, lp, 0);
                const half8 p1 = loadB(ping, lp, 1);
                #pragma unroll
                for (int mt = 0; mt < 4; ++mt) {
                    float4v acc = mfma16(aL2[mt * 2 + 0], p0, zero);
                    acc         = mfma16(aL2[mt * 2 + 1], p1, acc);
                    storeTile(pong, lp, mt, acc, bL2[mt]);
                }
            }
            {
                const half8 p0 = loadB(pong, lp, 0);
                const half8 p1 = loadB(pong, lp, 1);
                #pragma unroll
                for (int mt = 0; mt < 4; ++mt) {
                    float4v acc = mfma16(aL3[mt * 2 + 0], p0, zero);
                    acc         = mfma16(aL3[mt * 2 + 1], p1, acc);
                    storeTile(ping, lp, mt, acc, bL3[mt]);
                }
            }
            {
                const half8 p0 = loadB(ping, lp, 0);
                const half8 p1 = loadB(ping, lp, 1);
                float4v acc = mfma16(aL4[0], p0, zero);
                acc         = mfma16(aL4[1], p1, acc);
                float4v res;
                #pragma unroll
                for (int r = 0; r < 4; ++r)
                    res[r] = fmaf(acc[r], INV_SCALE, bL4[r]);
                const size_t ptg = (size_t)blockIdx.x * 256 + (size_t)wv * 64 + g * 32 + lp;
                *reinterpret_cast<float4v*>(out + ptg * 16 + quad * 4) = res;
            }
        }
    }
}

extern "C" void kernel_launch(void* const* d_in, const int* in_sizes, int n_in,
                              void* d_out, int out_size, void* d_ws, size_t ws_size,
                              hipStream_t stream) {
    const float*  coords = (const float*)d_in[0];
    const float2* tables = (const float2*)d_in[1];
    const float*  w_in   = (const float*)d_in[2];
    const float*  b_in   = (const float*)d_in[3];
    const float*  w_h0   = (const float*)d_in[4];
    const float*  b_h0   = (const float*)d_in[5];
    const float*  w_h1   = (const float*)d_in[6];
    const float*  b_h1   = (const float*)d_in[7];
    const float*  w_out  = (const float*)d_in[8];
    const float*  b_out  = (const float*)d_in[9];
    float* out = (float*)d_out;

    const int npts = in_sizes[0] / 3;      // 262144
    const size_t encBytes     = (size_t)npts * 32 * sizeof(half_t);     // 16.8 MB
    const size_t fragBytes    = (size_t)NFRAG * 64 * sizeof(half8);     // 22.5 KB
    const size_t compactBytes = (size_t)CG_TOTAL_PAD * sizeof(unsigned);// 270.8 KB

    // staged-grid geometry (64 chunks of 4096) requires npts == 262144 exactly
    if (ws_size >= encBytes + fragBytes + compactBytes && npts == 262144) {
        half_t*   encT    = (half_t*)d_ws;
        half8*    frags   = (half8*)((char*)d_ws + encBytes);
        unsigned* compact = (unsigned*)((char*)d_ws + encBytes + fragBytes);
        const int bpl = npts >> 8;
        // 12 hashed levels (phase A: 8*bpl, phase B: 4*bpl) + 22 wprep + 265 compact tails
        nerf_encode_h12<<<12 * bpl + NFRAG + CG_BLOCKS, 256, 0, stream>>>(
            coords, tables, w_in, w_h0, w_h1, w_out, frags, compact, encT, npts);
        // levels 0..3 from LDS-staged compact grids (4 levels x 64 chunks)
        nerf_encode_stage<<<4 * 64, 256, 0, stream>>>(coords, compact, encT, npts);
        nerf_mlp7<<<npts / 256, 256, 0, stream>>>(encT, frags,
                                                  b_in, b_h0, b_h1, b_out,
                                                  out, npts);
    } else {
        nerf_fused<<<npts / 256, 256, 0, stream>>>(coords, tables,
                                                   w_in, b_in, w_h0, b_h0,
                                                   w_h1, b_h1, w_out, b_out,
                                                   out, npts);
    }
}

// Round 7
// 191.932 us; speedup vs baseline: 1.0340x; 1.0340x over previous
//
#include <hip/hip_runtime.h>

#define NLVL 16
#define LOGT 19
#define TMASK ((1u << LOGT) - 1u)
#define SCALE 4096.0f
#define INV_SCALE (1.0f / 4096.0f)
#define NFRAG 22

// compact dense grids for levels 0..3 (res 16,20,25,32)
#define NCG 4
#define CG_TOTAL 67687          // 17^3 + 21^3 + 26^3 + 33^3
#define CG_TOTAL_PAD 67700      // 16B-aligned-per-level + vec-load slack
#define CG_BLOCKS 265           // ceil(67687/256)

typedef _Float16 half_t;
typedef half_t half8 __attribute__((ext_vector_type(8)));
typedef half_t half4 __attribute__((ext_vector_type(4)));
typedef half_t half2v __attribute__((ext_vector_type(2)));
typedef float  float4v __attribute__((ext_vector_type(4)));
typedef unsigned int uint4v __attribute__((ext_vector_type(4)));

__device__ __constant__ float RES_C[NLVL] = {16.f, 20.f, 25.f, 32.f, 40.f, 50.f, 64.f, 80.f,
                                             101.f, 128.f, 161.f, 203.f, 256.f, 322.f, 406.f, 512.f};
__device__ __constant__ int CG_SIZE[NCG] = {4913, 9261, 17576, 35937};
__device__ __constant__ int CG_OFF[NCG]  = {0, 4916, 14180, 31760};   // 4-uint aligned
__device__ __constant__ int CG_R1[NCG]   = {17, 21, 26, 33};          // res+1

__device__ __forceinline__ float4v mfma16(half8 a, half8 b, float4v c) {
    return __builtin_amdgcn_mfma_f32_16x16x32_f16(a, b, c, 0, 0, 0);
}

// ---------------- Kernel A: 12 hashed levels (4..15), 1.5 levels per XCD ----------------
// CONFIRMED R6: encode dropped 88.6 -> 72-76us (predicted 67-75); per-XCD L2
// request-rate model holds. Phase A (b < 8*bpl): level 4+(b&7) pinned 1:1 to XCD.
// Phase B (next 4*bpl): levels 12..15 each split across an XCD PAIR; each XCD's
// private L2 caches the full 4MB table (FETCH +2.6MB cold refill, as predicted).
// Tail blocks: 22 weight-prep frags + 265 compact-grid-build blocks.
__global__ __launch_bounds__(256, 8) void nerf_encode_h12(
    const float* __restrict__ coords,
    const float2* __restrict__ tab,
    const float* __restrict__ w_in, const float* __restrict__ w_h0,
    const float* __restrict__ w_h1, const float* __restrict__ w_out,
    half8* __restrict__ frags,
    unsigned* __restrict__ compact,
    half_t* __restrict__ encT, int npts)
{
    const int bpl   = npts >> 8;
    const int nHash = 12 * bpl;
    const int b     = blockIdx.x;

    if (b >= nHash) {                      // ---- tail: weight-prep + compact build ----
        const int tb = b - nHash;
        if (tb < NFRAG) {
            if (threadIdx.x < 64) {
                const int frag = tb;
                const int lane = threadIdx.x;
                const int m    = lane & 15;
                const int quad = lane >> 4;
                const float* W; int ncol, row, col;
                if (frag < 4)       { W = w_in;  ncol = 32; row = frag * 16 + m;      col = quad * 8; }
                else if (frag < 12) { const int f = frag - 4;
                                      W = w_h0;  ncol = 64; row = (f >> 1) * 16 + m;  col = (f & 1) * 32 + quad * 8; }
                else if (frag < 20) { const int f = frag - 12;
                                      W = w_h1;  ncol = 64; row = (f >> 1) * 16 + m;  col = (f & 1) * 32 + quad * 8; }
                else                { const int f = frag - 20;
                                      W = w_out; ncol = 64; row = m;                  col = f * 32 + quad * 8; }
                const float* p = W + row * ncol + col;
                half8 r;
                #pragma unroll
                for (int j = 0; j < 8; ++j) r[j] = (half_t)p[j];
                frags[frag * 64 + lane] = r;
            }
        } else {
            const int vid = (tb - NFRAG) * 256 + (int)threadIdx.x;
            if (vid < CG_TOTAL) {
                const int l = (vid >= 31750) ? 3 : (vid >= 14174) ? 2 : (vid >= 4913) ? 1 : 0;
                const int voff = (l == 3) ? 31750 : (l == 2) ? 14174 : (l == 1) ? 4913 : 0;
                const int v  = vid - voff;
                const int r1 = CG_R1[l];
                const int z  = v % r1;
                const int r2 = v / r1;
                const int y  = r2 % r1;
                const int x  = r2 / r1;
                const unsigned idx = ((unsigned)x
                                    ^ ((unsigned)y * 2654435761u)
                                    ^ ((unsigned)z * 805459861u)) & TMASK;
                const float2 tv = tab[(((unsigned)l) << LOGT) + idx];
                half2v h; h[0] = (half_t)tv.x; h[1] = (half_t)tv.y;   // fp16 round-trip exact
                compact[CG_OFF[l] + v] = __builtin_bit_cast(unsigned, h);
            }
        }
        return;
    }

    // ---- hashed-level mapping ----
    int l, pb;
    const int phaseA = 8 * bpl;
    if (b < phaseA) { l = 4 + (b & 7); pb = b >> 3; }
    else {
        const int b2 = b - phaseA;                 // [0, 4*bpl)
        l  = 12 + ((b2 & 7) >> 1);
        pb = ((b2 >> 3) << 1) + (b2 & 1);          // bijection onto [0, bpl)
    }

    const int side = threadIdx.x & 1;              // 0 = floor-x, 1 = ceil-x
    const int base = pb * 256 + (threadIdx.x >> 1);
    const int p0 = base, p1 = base + 128;

    const float r = RES_C[l];
    const float2* __restrict__ bp = tab + (((unsigned)l) << LOGT);

    const float ax = coords[p0 * 3 + 0] * r, ay = coords[p0 * 3 + 1] * r, az = coords[p0 * 3 + 2] * r;
    const float afx = floorf(ax), afy = floorf(ay), afz = floorf(az);
    const float agx = ceilf(ax),  agy = ceilf(ay),  agz = ceilf(az);
    const unsigned ahx = side ? (unsigned)(int)agx : (unsigned)(int)afx;
    const float    awx = side ? (ax - afx) : (agx - ax);
    const unsigned ahfy = (unsigned)(int)afy * 2654435761u;
    const unsigned ahgy = (unsigned)(int)agy * 2654435761u;
    const unsigned ahfz = (unsigned)(int)afz * 805459861u;
    const unsigned ahgz = (unsigned)(int)agz * 805459861u;
    const float aty = ay - afy, atz = az - afz, auy = agy - ay, auz = agz - az;

    const float bx = coords[p1 * 3 + 0] * r, by = coords[p1 * 3 + 1] * r, bz = coords[p1 * 3 + 2] * r;
    const float bfx = floorf(bx), bfy = floorf(by), bfz = floorf(bz);
    const float bgx = ceilf(bx),  bgy = ceilf(by),  bgz = ceilf(bz);
    const unsigned bhx = side ? (unsigned)(int)bgx : (unsigned)(int)bfx;
    const float    bwx = side ? (bx - bfx) : (bgx - bx);
    const unsigned bhfy = (unsigned)(int)bfy * 2654435761u;
    const unsigned bhgy = (unsigned)(int)bgy * 2654435761u;
    const unsigned bhfz = (unsigned)(int)bfz * 805459861u;
    const unsigned bhgz = (unsigned)(int)bgz * 805459861u;
    const float bty = by - bfy, btz = bz - bfz, buy = bgy - by, buz = bgz - bz;

    const float2 a0 = bp[(ahx ^ ahfy ^ ahfz) & TMASK];
    const float2 a1 = bp[(ahx ^ ahfy ^ ahgz) & TMASK];
    const float2 a2 = bp[(ahx ^ ahgy ^ ahfz) & TMASK];
    const float2 a3 = bp[(ahx ^ ahgy ^ ahgz) & TMASK];
    const float2 b0 = bp[(bhx ^ bhfy ^ bhfz) & TMASK];
    const float2 b1 = bp[(bhx ^ bhfy ^ bhgz) & TMASK];
    const float2 b2 = bp[(bhx ^ bhgy ^ bhfz) & TMASK];
    const float2 b3 = bp[(bhx ^ bhgy ^ bhgz) & TMASK];

    const float aw0 = awx * auy * auz, aw1 = awx * auy * atz;
    const float aw2 = awx * aty * auz, aw3 = awx * aty * atz;
    const float bw0 = bwx * buy * buz, bw1 = bwx * buy * btz;
    const float bw2 = bwx * bty * buz, bw3 = bwx * bty * btz;

    float ae0 = aw0 * a0.x + aw1 * a1.x + aw2 * a2.x + aw3 * a3.x;
    float ae1 = aw0 * a0.y + aw1 * a1.y + aw2 * a2.y + aw3 * a3.y;
    float be0 = bw0 * b0.x + bw1 * b1.x + bw2 * b2.x + bw3 * b3.x;
    float be1 = bw0 * b0.y + bw1 * b1.y + bw2 * b2.y + bw3 * b3.y;

    ae0 += __shfl_xor(ae0, 1, 64);
    ae1 += __shfl_xor(ae1, 1, 64);
    be0 += __shfl_xor(be0, 1, 64);
    be1 += __shfl_xor(be1, 1, 64);

    if (side == 0) {
        half2v h0; h0[0] = (half_t)(ae0 * SCALE); h0[1] = (half_t)(ae1 * SCALE);
        half2v h1; h1[0] = (half_t)(be0 * SCALE); h1[1] = (half_t)(be1 * SCALE);
        *reinterpret_cast<half2v*>(&encT[((size_t)l * npts + p0) * 2]) = h0;
        *reinterpret_cast<half2v*>(&encT[((size_t)l * npts + p1) * 2]) = h1;
    }
}

// ---------------- Kernel A2: levels 0..3 from LDS-staged compact dense grids ----------------
// R7 fix: R6 ran this at 256 thr x 1 block/CU = 4 waves/CU -> latency-bound ~17us
// (ate the entire encode win). Now 1024 threads/block (16 waves/CU at the same
// 143.7 KB LDS, 1 block/CU): staging parallelizes 4x and each thread does 4
// point-iterations instead of 16 -> predicted ~4-6us.
// Geometry fixed to npts == 262144 (guarded in launcher).
__global__ __launch_bounds__(1024, 1) void nerf_encode_stage(
    const float* __restrict__ coords,
    const unsigned* __restrict__ compact,
    half_t* __restrict__ encT, int npts)
{
    __shared__ unsigned sgrid[35940];              // 143,760 B (level-3 grid + vec slack)

    const int s     = blockIdx.x;
    const int l     = s >> 6;
    const int chunk = s & 63;
    const int t     = threadIdx.x;

    const int sz = CG_SIZE[l];
    const unsigned* __restrict__ src = compact + CG_OFF[l];
    const int n4 = (sz + 3) >> 2;
    for (int i = t; i < n4; i += 1024) {
        const uint4v v = *reinterpret_cast<const uint4v*>(src + i * 4);
        *reinterpret_cast<uint4v*>(&sgrid[i * 4]) = v;
    }
    __syncthreads();

    const float r  = RES_C[l];
    const int   r1 = CG_R1[l];
    const int   p0 = chunk * 4096 + t;

    #pragma unroll 4
    for (int k = 0; k < 4; ++k) {
        const int p = p0 + k * 1024;
        const float cx = coords[p * 3 + 0], cy = coords[p * 3 + 1], cz = coords[p * 3 + 2];
        const float sx = cx * r, sy = cy * r, szf = cz * r;
        const float fx = floorf(sx), fy = floorf(sy), fz = floorf(szf);
        const float gx = ceilf(sx),  gy = ceilf(sy),  gz = ceilf(szf);
        const int ixf = (int)fx, iyf = (int)fy, izf = (int)fz;
        const int ixg = (int)gx, iyg = (int)gy, izg = (int)gz;

        const float wxf = gx - sx, wxc = sx - fx;
        const float uy = gy - sy, ty = sy - fy;
        const float uz = gz - szf, tz = szf - fz;

        const int bf = ixf * r1, bg = ixg * r1;
        const int rf = (bf + iyf) * r1, rF = (bf + iyg) * r1;
        const int rg = (bg + iyf) * r1, rG = (bg + iyg) * r1;

        const half2v c0 = __builtin_bit_cast(half2v, sgrid[rf + izf]);
        const half2v c1 = __builtin_bit_cast(half2v, sgrid[rf + izg]);
        const half2v c2 = __builtin_bit_cast(half2v, sgrid[rF + izf]);
        const half2v c3 = __builtin_bit_cast(half2v, sgrid[rF + izg]);
        const half2v c4 = __builtin_bit_cast(half2v, sgrid[rg + izf]);
        const half2v c5 = __builtin_bit_cast(half2v, sgrid[rg + izg]);
        const half2v c6 = __builtin_bit_cast(half2v, sgrid[rG + izf]);
        const half2v c7 = __builtin_bit_cast(half2v, sgrid[rG + izg]);

        const float w0 = wxf * uy * uz, w1 = wxf * uy * tz;
        const float w2 = wxf * ty * uz, w3 = wxf * ty * tz;
        const float w4 = wxc * uy * uz, w5 = wxc * uy * tz;
        const float w6 = wxc * ty * uz, w7 = wxc * ty * tz;

        float e0f = w0 * (float)c0[0] + w1 * (float)c1[0] + w2 * (float)c2[0] + w3 * (float)c3[0];
        float e1f = w0 * (float)c0[1] + w1 * (float)c1[1] + w2 * (float)c2[1] + w3 * (float)c3[1];
        float e0c = w4 * (float)c4[0] + w5 * (float)c5[0] + w6 * (float)c6[0] + w7 * (float)c7[0];
        float e1c = w4 * (float)c4[1] + w5 * (float)c5[1] + w6 * (float)c6[1] + w7 * (float)c7[1];
        const float e0 = e0f + e0c;
        const float e1 = e1f + e1c;

        half2v h; h[0] = (half_t)(e0 * SCALE); h[1] = (half_t)(e1 * SCALE);
        *reinterpret_cast<half2v*>(&encT[((size_t)l * npts + p) * 2]) = h;
    }
}

// ---------------- In-register layer transition (proven correct: absmax unchanged R1-R6) ----------------
__device__ __forceinline__ unsigned pack_relu2(float x, float y) {
    half2v h;
    h[0] = (half_t)fmaxf(x, 0.f);
    h[1] = (half_t)fmaxf(y, 0.f);
    return __builtin_bit_cast(unsigned, h);
}

__device__ __forceinline__ void xpose_relu(const float4v acc[4], int lane,
                                           half8& b0, half8& b1) {
    unsigned X[4], Y[4];
    X[0] = pack_relu2(acc[0][0], acc[0][1]);
    X[1] = pack_relu2(acc[0][2], acc[0][3]);
    X[2] = pack_relu2(acc[2][0], acc[2][1]);
    X[3] = pack_relu2(acc[2][2], acc[2][3]);
    Y[0] = pack_relu2(acc[1][0], acc[1][1]);
    Y[1] = pack_relu2(acc[1][2], acc[1][3]);
    Y[2] = pack_relu2(acc[3][0], acc[3][1]);
    Y[3] = pack_relu2(acc[3][2], acc[3][3]);
    const bool lo = (lane & 32) == 0;
    const bool ev = (lane & 16) == 0;
    uint4v u0, u1;
    #pragma unroll
    for (int j = 0; j < 4; ++j) {
        const unsigned s1 = lo ? Y[j] : X[j];
        const unsigned t1 = __shfl_xor(s1, 32, 64);
        const unsigned A1 = lo ? X[j] : t1;
        const unsigned B1 = lo ? t1 : Y[j];
        const unsigned s2 = ev ? B1 : A1;
        const unsigned t2 = __shfl_xor(s2, 16, 64);
        const unsigned a2 = ev ? A1 : t2;
        const unsigned b2 = ev ? t2 : B1;
        if (j < 2) { u0[j] = a2; u0[2 + j] = b2; }
        else       { u1[j - 2] = a2; u1[j] = b2; }
    }
    b0 = __builtin_bit_cast(half8, u0);
    b1 = __builtin_bit_cast(half8, u1);
}

// ---------------- Kernel B: register-transpose MLP (measured ~11us; unchanged) ----------------
__global__ __launch_bounds__(256, 3) void nerf_mlp7(
    const half_t* __restrict__ encT,
    const half8* __restrict__ frags,
    const float* __restrict__ b_in, const float* __restrict__ b_h0,
    const float* __restrict__ b_h1, const float* __restrict__ b_out,
    float* __restrict__ out, int npts)
{
    const int t    = threadIdx.x;
    const int lane = t & 63;
    const int wv   = t >> 6;
    const int m    = lane & 15;
    const int quad = lane >> 4;
    const size_t pbase = (size_t)blockIdx.x * 256 + (size_t)wv * 64;

    half8 be[4];
    #pragma unroll
    for (int T = 0; T < 4; ++T) {
        #pragma unroll
        for (int d = 0; d < 4; ++d) {
            const int L = quad * 4 + d;
            const half2v v = *reinterpret_cast<const half2v*>(
                &encT[((size_t)L * npts + pbase + T * 16 + m) * 2]);
            be[T][d * 2 + 0] = v[0];
            be[T][d * 2 + 1] = v[1];
        }
    }

    half8 bf0[4], bf1[4];

    // ---- layer 1: 32 -> 64 ----
    {
        half8 w[4];
        #pragma unroll
        for (int f = 0; f < 4; ++f) w[f] = frags[(0 + f) * 64 + lane];
        float4v cin[4];
        #pragma unroll
        for (int mt = 0; mt < 4; ++mt)
            cin[mt] = (*reinterpret_cast<const float4v*>(b_in + mt * 16 + quad * 4)) * SCALE;
        #pragma unroll
        for (int T = 0; T < 4; ++T) {
            float4v acc[4];
            #pragma unroll
            for (int mt = 0; mt < 4; ++mt) acc[mt] = mfma16(w[mt], be[T], cin[mt]);
            xpose_relu(acc, lane, bf0[T], bf1[T]);
        }
    }
    // ---- layer 2: 64 -> 64 ----
    {
        half8 w[8];
        #pragma unroll
        for (int f = 0; f < 8; ++f) w[f] = frags[(4 + f) * 64 + lane];
        float4v cin[4];
        #pragma unroll
        for (int mt = 0; mt < 4; ++mt)
            cin[mt] = (*reinterpret_cast<const float4v*>(b_h0 + mt * 16 + quad * 4)) * SCALE;
        #pragma unroll
        for (int T = 0; T < 4; ++T) {
            float4v acc[4];
            #pragma unroll
            for (int mt = 0; mt < 4; ++mt) {
                acc[mt] = mfma16(w[mt * 2 + 0], bf0[T], cin[mt]);
                acc[mt] = mfma16(w[mt * 2 + 1], bf1[T], acc[mt]);
            }
            xpose_relu(acc, lane, bf0[T], bf1[T]);
        }
    }
    // ---- layer 3: 64 -> 64 ----
    {
        half8 w[8];
        #pragma unroll
        for (int f = 0; f < 8; ++f) w[f] = frags[(12 + f) * 64 + lane];
        float4v cin[4];
        #pragma unroll
        for (int mt = 0; mt < 4; ++mt)
            cin[mt] = (*reinterpret_cast<const float4v*>(b_h1 + mt * 16 + quad * 4)) * SCALE;
        #pragma unroll
        for (int T = 0; T < 4; ++T) {
            float4v acc[4];
            #pragma unroll
            for (int mt = 0; mt < 4; ++mt) {
                acc[mt] = mfma16(w[mt * 2 + 0], bf0[T], cin[mt]);
                acc[mt] = mfma16(w[mt * 2 + 1], bf1[T], acc[mt]);
            }
            xpose_relu(acc, lane, bf0[T], bf1[T]);
        }
    }
    // ---- layer 4: 64 -> 16, coalesced float4 store ----
    {
        const half8 w0 = frags[20 * 64 + lane];
        const half8 w1 = frags[21 * 64 + lane];
        const float4v b4 = *reinterpret_cast<const float4v*>(b_out + quad * 4);
        const float4v zero = {0.f, 0.f, 0.f, 0.f};
        #pragma unroll
        for (int T = 0; T < 4; ++T) {
            float4v acc = mfma16(w0, bf0[T], zero);
            acc         = mfma16(w1, bf1[T], acc);
            float4v res;
            #pragma unroll
            for (int r = 0; r < 4; ++r) res[r] = fmaf(acc[r], INV_SCALE, b4[r]);
            *reinterpret_cast<float4v*>(out + (pbase + T * 16 + m) * 16 + quad * 4) = res;
        }
    }
}

// ---------------- Fallback: fused kernel (used only if ws too small; unchanged) ----------------
__global__ __launch_bounds__(256, 2) void nerf_fused(
    const float* __restrict__ coords,
    const float2* __restrict__ tab,
    const float* __restrict__ w_in, const float* __restrict__ b_in,
    const float* __restrict__ w_h0, const float* __restrict__ b_h0,
    const float* __restrict__ w_h1, const float* __restrict__ b_h1,
    const float* __restrict__ w_out, const float* __restrict__ b_out,
    float* __restrict__ out, int npts)
{
    __shared__ half_t encS[256 * 40];
    __shared__ half_t actS[4][2][32 * 64];

    const int t    = threadIdx.x;
    const int lane = t & 63;
    const int wv   = t >> 6;
    const int m    = lane & 15;
    const int quad = lane >> 4;
    const int pt = blockIdx.x * 256 + t;

    {
        const float cx = coords[pt * 3 + 0];
        const float cy = coords[pt * 3 + 1];
        const float cz = coords[pt * 3 + 2];
        float enc[32];
        #pragma unroll
        for (int l = 0; l < NLVL; ++l) {
            const float r = RES_C[l];
            const float sx = cx * r, sy = cy * r, sz = cz * r;
            const float fx = floorf(sx), fy = floorf(sy), fz = floorf(sz);
            const float gx = ceilf(sx),  gy = ceilf(sy),  gz = ceilf(sz);
            const unsigned hfx = (unsigned)(int)fx;
            const unsigned hgx = (unsigned)(int)gx;
            const unsigned hfy = (unsigned)(int)fy * 2654435761u;
            const unsigned hgy = (unsigned)(int)gy * 2654435761u;
            const unsigned hfz = (unsigned)(int)fz * 805459861u;
            const unsigned hgz = (unsigned)(int)gz * 805459861u;
            const float tx = sx - fx, ty = sy - fy, tz = sz - fz;
            const float ux = gx - sx, uy = gy - sy, uz = gz - sz;
            const unsigned lbase = ((unsigned)l) << LOGT;
            float e0 = 0.f, e1 = 0.f;
            #pragma unroll
            for (int o = 0; o < 8; ++o) {
                const unsigned h = ((o & 4) ? hgx : hfx)
                                 ^ ((o & 2) ? hgy : hfy)
                                 ^ ((o & 1) ? hgz : hfz);
                const unsigned idx = h & TMASK;
                const float w = (((o & 4) ? tx : ux)
                              *  ((o & 2) ? ty : uy))
                              *  ((o & 1) ? tz : uz);
                const float2 fv = tab[lbase + idx];
                e0 = fmaf(w, fv.x, e0);
                e1 = fmaf(w, fv.y, e1);
            }
            enc[2 * l + 0] = e0;
            enc[2 * l + 1] = e1;
        }
        #pragma unroll
        for (int c = 0; c < 4; ++c) {
            half8 h8;
            #pragma unroll
            for (int j = 0; j < 8; ++j) h8[j] = (half_t)(enc[c * 8 + j] * SCALE);
            *reinterpret_cast<half8*>(&encS[t * 40 + c * 8]) = h8;
        }
    }

    auto loadA = [&](const float* __restrict__ W, int ncol, int row, int col) -> half8 {
        const float* p = W + row * ncol + col;
        const float4v lo = *reinterpret_cast<const float4v*>(p);
        const float4v hi = *reinterpret_cast<const float4v*>(p + 4);
        half8 r;
        r[0] = (half_t)lo[0]; r[1] = (half_t)lo[1]; r[2] = (half_t)lo[2]; r[3] = (half_t)lo[3];
        r[4] = (half_t)hi[0]; r[5] = (half_t)hi[1]; r[6] = (half_t)hi[2]; r[7] = (half_t)hi[3];
        return r;
    };

    half8 aL1[4], aL2[8], aL3[8], aL4[2];
    #pragma unroll
    for (int mt = 0; mt < 4; ++mt) aL1[mt] = loadA(w_in, 32, mt * 16 + m, quad * 8);
    #pragma unroll
    for (int mt = 0; mt < 4; ++mt) {
        aL2[mt * 2 + 0] = loadA(w_h0, 64, mt * 16 + m, 0 * 32 + quad * 8);
        aL2[mt * 2 + 1] = loadA(w_h0, 64, mt * 16 + m, 1 * 32 + quad * 8);
        aL3[mt * 2 + 0] = loadA(w_h1, 64, mt * 16 + m, 0 * 32 + quad * 8);
        aL3[mt * 2 + 1] = loadA(w_h1, 64, mt * 16 + m, 1 * 32 + quad * 8);
    }
    aL4[0] = loadA(w_out, 64, m, 0 * 32 + quad * 8);
    aL4[1] = loadA(w_out, 64, m, 1 * 32 + quad * 8);

    float4v bL1[4], bL2[4], bL3[4], bL4;
    #pragma unroll
    for (int mt = 0; mt < 4; ++mt) {
        bL1[mt] = *reinterpret_cast<const float4v*>(b_in + mt * 16 + quad * 4);
        bL2[mt] = *reinterpret_cast<const float4v*>(b_h0 + mt * 16 + quad * 4);
        bL3[mt] = *reinterpret_cast<const float4v*>(b_h1 + mt * 16 + quad * 4);
    }
    bL4 = *reinterpret_cast<const float4v*>(b_out + quad * 4);

    half_t* const ping = &actS[wv][0][0];
    half_t* const pong = &actS[wv][1][0];
    const float4v zero = {0.f, 0.f, 0.f, 0.f};

    auto storeTile = [&](half_t* buf, int lp, int mt, float4v acc, float4v bias) {
        half4 h4;
        #pragma unroll
        for (int r = 0; r < 4; ++r)
            h4[r] = (half_t)fmaxf(fmaf(bias[r], SCALE, acc[r]), 0.f);
        const int c16  = mt * 2 + (quad >> 1);
        const int phys = c16 ^ (lp & 7);
        *reinterpret_cast<half4*>(&buf[lp * 64 + phys * 8 + (quad & 1) * 4]) = h4;
    };
    auto loadB = [&](half_t* buf, int lp, int h) -> half8 {
        const int phys = (h * 4 + quad) ^ (lp & 7);
        return *reinterpret_cast<const half8*>(&buf[lp * 64 + phys * 8]);
    };

    for (int g = 0; g < 2; ++g) {
        #pragma unroll
        for (int nt = 0; nt < 2; ++nt) {
            const int lp   = nt * 16 + m;
            const int prow = wv * 64 + g * 32 + lp;
            const half8 bfr = *reinterpret_cast<const half8*>(&encS[prow * 40 + quad * 8]);
            #pragma unroll
            for (int mt = 0; mt < 4; ++mt) {
                float4v acc = mfma16(aL1[mt], bfr, zero);
                storeTile(ping, lp, mt, acc, bL1[mt]);
            }
            {
                const half8 p0 = loadB(ping, lp, 0);
                const half8 p1 = loadB(ping, lp, 1);
                #pragma unroll
                for (int mt = 0; mt < 4; ++mt) {
                    float4v acc = mfma16(aL2[mt * 2 + 0], p0, zero);
                    acc         = mfma16(aL2[mt * 2 + 1], p1, acc);
                    storeTile(pong, lp, mt, acc, bL2[mt]);
                }
            }
            {
                const half8 p0 = loadB(pong, lp, 0);
                const half8 p1 = loadB(pong, lp, 1);
                #pragma unroll
                for (int mt = 0; mt < 4; ++mt) {
                    float4v acc = mfma16(aL3[mt * 2 + 0], p0, zero);
                    acc         = mfma16(aL3[mt * 2 + 1], p1, acc);
                    storeTile(ping, lp, mt, acc, bL3[mt]);
                }
            }
            {
                const half8 p0 = loadB(ping, lp, 0);
                const half8 p1 = loadB(ping, lp, 1);
                float4v acc = mfma16(aL4[0], p0, zero);
                acc         = mfma16(aL4[1], p1, acc);
                float4v res;
                #pragma unroll
                for (int r = 0; r < 4; ++r)
                    res[r] = fmaf(acc[r], INV_SCALE, bL4[r]);
                const size_t ptg = (size_t)blockIdx.x * 256 + (size_t)wv * 64 + g * 32 + lp;
                *reinterpret_cast<float4v*>(out + ptg * 16 + quad * 4) = res;
            }
        }
    }
}

extern "C" void kernel_launch(void* const* d_in, const int* in_sizes, int n_in,
                              void* d_out, int out_size, void* d_ws, size_t ws_size,
                              hipStream_t stream) {
    const float*  coords = (const float*)d_in[0];
    const float2* tables = (const float2*)d_in[1];
    const float*  w_in   = (const float*)d_in[2];
    const float*  b_in   = (const float*)d_in[3];
    const float*  w_h0   = (const float*)d_in[4];
    const float*  b_h0   = (const float*)d_in[5];
    const float*  w_h1   = (const float*)d_in[6];
    const float*  b_h1   = (const float*)d_in[7];
    const float*  w_out  = (const float*)d_in[8];
    const float*  b_out  = (const float*)d_in[9];
    float* out = (float*)d_out;

    const int npts = in_sizes[0] / 3;      // 262144
    const size_t encBytes     = (size_t)npts * 32 * sizeof(half_t);     // 16.8 MB
    const size_t fragBytes    = (size_t)NFRAG * 64 * sizeof(half8);     // 22.5 KB
    const size_t compactBytes = (size_t)CG_TOTAL_PAD * sizeof(unsigned);// 270.8 KB

    // staged-grid geometry (64 chunks of 4096) requires npts == 262144 exactly
    if (ws_size >= encBytes + fragBytes + compactBytes && npts == 262144) {
        half_t*   encT    = (half_t*)d_ws;
        half8*    frags   = (half8*)((char*)d_ws + encBytes);
        unsigned* compact = (unsigned*)((char*)d_ws + encBytes + fragBytes);
        const int bpl = npts >> 8;
        // 12 hashed levels (phase A: 8*bpl, phase B: 4*bpl) + 22 wprep + 265 compact tails
        nerf_encode_h12<<<12 * bpl + NFRAG + CG_BLOCKS, 256, 0, stream>>>(
            coords, tables, w_in, w_h0, w_h1, w_out, frags, compact, encT, npts);
        // levels 0..3 from LDS-staged compact grids (4 levels x 64 chunks, 1024 thr)
        nerf_encode_stage<<<4 * 64, 1024, 0, stream>>>(coords, compact, encT, npts);
        nerf_mlp7<<<npts / 256, 256, 0, stream>>>(encT, frags,
                                                  b_in, b_h0, b_h1, b_out,
                                                  out, npts);
    } else {
        nerf_fused<<<npts / 256, 256, 0, stream>>>(coords, tables,
                                                   w_in, b_in, w_h0, b_h0,
                                                   w_h1, b_h1, w_out, b_out,
                                                   out, npts);
    }
}

// Round 8
// 191.717 us; speedup vs baseline: 1.0352x; 1.0011x over previous
//
#include <hip/hip_runtime.h>

#define NLVL 16
#define LOGT 19
#define TMASK ((1u << LOGT) - 1u)
#define SCALE 4096.0f
#define INV_SCALE (1.0f / 4096.0f)
#define NFRAG 22

// compact dense grids for levels 0..3 (res 16,20,25,32)
#define NCG 4
#define CG_TOTAL_PAD 67700      // CG_OFF[3] + 35940 (level sizes + zeroed gaps/pad)
#define CG_BLOCKS 265           // ceil(67700/256)

typedef _Float16 half_t;
typedef half_t half8 __attribute__((ext_vector_type(8)));
typedef half_t half4 __attribute__((ext_vector_type(4)));
typedef half_t half2v __attribute__((ext_vector_type(2)));
typedef float  float4v __attribute__((ext_vector_type(4)));
typedef unsigned int uint4v __attribute__((ext_vector_type(4)));

__device__ __constant__ float RES_C[NLVL] = {16.f, 20.f, 25.f, 32.f, 40.f, 50.f, 64.f, 80.f,
                                             101.f, 128.f, 161.f, 203.f, 256.f, 322.f, 406.f, 512.f};
__device__ __constant__ int CG_SIZE[NCG] = {4913, 9261, 17576, 35937};
__device__ __constant__ int CG_OFF[NCG]  = {0, 4916, 14180, 31760};   // 4-uint aligned; gaps zeroed
__device__ __constant__ int CG_R1[NCG]   = {17, 21, 26, 33};          // res+1

__device__ __forceinline__ float4v mfma16(half8 a, half8 b, float4v c) {
    return __builtin_amdgcn_mfma_f32_16x16x32_f16(a, b, c, 0, 0, 0);
}

// ---------------- Kernel A: 12 hashed levels (4..15), 1.5 levels per XCD ----------------
// CONFIRMED R6/R7: encode at 72-76us (model 67us, 90%); per-XCD L2 request-rate
// wall holds. Phase A (b < 8*bpl): level 4+(b&7) pinned 1:1 to XCD. Phase B
// (next 4*bpl): levels 12..15 each split across an XCD PAIR.
// Tail blocks: 22 weight-prep frags + 265 compact-grid-build blocks.
// R8: compact build now covers the FULL padded index space [0, CG_TOTAL_PAD) and
// zeroes gap/pad slots -- required because the stage kernel's fused z-pair reads
// can touch the entry one past each level's last (always with weight +-0, but it
// must be finite, not workspace garbage).
__global__ __launch_bounds__(256, 8) void nerf_encode_h12(
    const float* __restrict__ coords,
    const float2* __restrict__ tab,
    const float* __restrict__ w_in, const float* __restrict__ w_h0,
    const float* __restrict__ w_h1, const float* __restrict__ w_out,
    half8* __restrict__ frags,
    unsigned* __restrict__ compact,
    half_t* __restrict__ encT, int npts)
{
    const int bpl   = npts >> 8;
    const int nHash = 12 * bpl;
    const int b     = blockIdx.x;

    if (b >= nHash) {                      // ---- tail: weight-prep + compact build ----
        const int tb = b - nHash;
        if (tb < NFRAG) {
            if (threadIdx.x < 64) {
                const int frag = tb;
                const int lane = threadIdx.x;
                const int m    = lane & 15;
                const int quad = lane >> 4;
                const float* W; int ncol, row, col;
                if (frag < 4)       { W = w_in;  ncol = 32; row = frag * 16 + m;      col = quad * 8; }
                else if (frag < 12) { const int f = frag - 4;
                                      W = w_h0;  ncol = 64; row = (f >> 1) * 16 + m;  col = (f & 1) * 32 + quad * 8; }
                else if (frag < 20) { const int f = frag - 12;
                                      W = w_h1;  ncol = 64; row = (f >> 1) * 16 + m;  col = (f & 1) * 32 + quad * 8; }
                else                { const int f = frag - 20;
                                      W = w_out; ncol = 64; row = m;                  col = f * 32 + quad * 8; }
                const float* p = W + row * ncol + col;
                half8 r;
                #pragma unroll
                for (int j = 0; j < 8; ++j) r[j] = (half_t)p[j];
                frags[frag * 64 + lane] = r;
            }
        } else {
            const int vid = (tb - NFRAG) * 256 + (int)threadIdx.x;
            if (vid < CG_TOTAL_PAD) {
                const int l = (vid >= 31760) ? 3 : (vid >= 14180) ? 2 : (vid >= 4916) ? 1 : 0;
                const int v = vid - CG_OFF[l];
                unsigned wv = 0u;                       // gap/pad slots -> zero (finite)
                if (v < CG_SIZE[l]) {
                    const int r1 = CG_R1[l];
                    const int z  = v % r1;
                    const int r2 = v / r1;
                    const int y  = r2 % r1;
                    const int x  = r2 / r1;
                    const unsigned idx = ((unsigned)x
                                        ^ ((unsigned)y * 2654435761u)
                                        ^ ((unsigned)z * 805459861u)) & TMASK;
                    const float2 tv = tab[(((unsigned)l) << LOGT) + idx];
                    half2v h; h[0] = (half_t)tv.x; h[1] = (half_t)tv.y;  // fp16 round-trip exact
                    wv = __builtin_bit_cast(unsigned, h);
                }
                compact[vid] = wv;
            }
        }
        return;
    }

    // ---- hashed-level mapping ----
    int l, pb;
    const int phaseA = 8 * bpl;
    if (b < phaseA) { l = 4 + (b & 7); pb = b >> 3; }
    else {
        const int b2 = b - phaseA;                 // [0, 4*bpl)
        l  = 12 + ((b2 & 7) >> 1);
        pb = ((b2 >> 3) << 1) + (b2 & 1);          // bijection onto [0, bpl)
    }

    const int side = threadIdx.x & 1;              // 0 = floor-x, 1 = ceil-x
    const int base = pb * 256 + (threadIdx.x >> 1);
    const int p0 = base, p1 = base + 128;

    const float r = RES_C[l];
    const float2* __restrict__ bp = tab + (((unsigned)l) << LOGT);

    const float ax = coords[p0 * 3 + 0] * r, ay = coords[p0 * 3 + 1] * r, az = coords[p0 * 3 + 2] * r;
    const float afx = floorf(ax), afy = floorf(ay), afz = floorf(az);
    const float agx = ceilf(ax),  agy = ceilf(ay),  agz = ceilf(az);
    const unsigned ahx = side ? (unsigned)(int)agx : (unsigned)(int)afx;
    const float    awx = side ? (ax - afx) : (agx - ax);
    const unsigned ahfy = (unsigned)(int)afy * 2654435761u;
    const unsigned ahgy = (unsigned)(int)agy * 2654435761u;
    const unsigned ahfz = (unsigned)(int)afz * 805459861u;
    const unsigned ahgz = (unsigned)(int)agz * 805459861u;
    const float aty = ay - afy, atz = az - afz, auy = agy - ay, auz = agz - az;

    const float bx = coords[p1 * 3 + 0] * r, by = coords[p1 * 3 + 1] * r, bz = coords[p1 * 3 + 2] * r;
    const float bfx = floorf(bx), bfy = floorf(by), bfz = floorf(bz);
    const float bgx = ceilf(bx),  bgy = ceilf(by),  bgz = ceilf(bz);
    const unsigned bhx = side ? (unsigned)(int)bgx : (unsigned)(int)bfx;
    const float    bwx = side ? (bx - bfx) : (bgx - bx);
    const unsigned bhfy = (unsigned)(int)bfy * 2654435761u;
    const unsigned bhgy = (unsigned)(int)bgy * 2654435761u;
    const unsigned bhfz = (unsigned)(int)bfz * 805459861u;
    const unsigned bhgz = (unsigned)(int)bgz * 805459861u;
    const float bty = by - bfy, btz = bz - bfz, buy = bgy - by, buz = bgz - bz;

    const float2 a0 = bp[(ahx ^ ahfy ^ ahfz) & TMASK];
    const float2 a1 = bp[(ahx ^ ahfy ^ ahgz) & TMASK];
    const float2 a2 = bp[(ahx ^ ahgy ^ ahfz) & TMASK];
    const float2 a3 = bp[(ahx ^ ahgy ^ ahgz) & TMASK];
    const float2 b0 = bp[(bhx ^ bhfy ^ bhfz) & TMASK];
    const float2 b1 = bp[(bhx ^ bhfy ^ bhgz) & TMASK];
    const float2 b2 = bp[(bhx ^ bhgy ^ bhfz) & TMASK];
    const float2 b3 = bp[(bhx ^ bhgy ^ bhgz) & TMASK];

    const float aw0 = awx * auy * auz, aw1 = awx * auy * atz;
    const float aw2 = awx * aty * auz, aw3 = awx * aty * atz;
    const float bw0 = bwx * buy * buz, bw1 = bwx * buy * btz;
    const float bw2 = bwx * bty * buz, bw3 = bwx * bty * btz;

    float ae0 = aw0 * a0.x + aw1 * a1.x + aw2 * a2.x + aw3 * a3.x;
    float ae1 = aw0 * a0.y + aw1 * a1.y + aw2 * a2.y + aw3 * a3.y;
    float be0 = bw0 * b0.x + bw1 * b1.x + bw2 * b2.x + bw3 * b3.x;
    float be1 = bw0 * b0.y + bw1 * b1.y + bw2 * b2.y + bw3 * b3.y;

    ae0 += __shfl_xor(ae0, 1, 64);
    ae1 += __shfl_xor(ae1, 1, 64);
    be0 += __shfl_xor(be0, 1, 64);
    be1 += __shfl_xor(be1, 1, 64);

    if (side == 0) {
        half2v h0; h0[0] = (half_t)(ae0 * SCALE); h0[1] = (half_t)(ae1 * SCALE);
        half2v h1; h1[0] = (half_t)(be0 * SCALE); h1[1] = (half_t)(be1 * SCALE);
        *reinterpret_cast<half2v*>(&encT[((size_t)l * npts + p0) * 2]) = h0;
        *reinterpret_cast<half2v*>(&encT[((size_t)l * npts + p1) * 2]) = h1;
    }
}

// ---------------- Kernel A2: levels 0..3 from LDS-staged compact dense grids ----------------
// R8 changes (from measured ~8.7us in R7):
//  * fused z-pair LDS reads: the two z-corners are adjacent words (idx, idx+1) --
//    written as s[i], s[i+1] so hipcc emits ds_read2_b32: 8 -> 4 LDS instructions
//    per point. The +1 slot in the z-degenerate (ceil==floor) case carries weight
//    exactly +-0 and reads a finite staged value (gaps/pad zeroed in build;
//    staging rounded up to (sz+4)>>2 quads so entry [sz] is always staged).
//    Sum is bit-identical.
//  * coord loads for all 4 iterations batched before compute (latency decouple).
__global__ __launch_bounds__(1024, 1) void nerf_encode_stage(
    const float* __restrict__ coords,
    const unsigned* __restrict__ compact,
    half_t* __restrict__ encT, int npts)
{
    __shared__ unsigned sgrid[35940];              // 143,760 B (level-3 grid + pad)

    const int s     = blockIdx.x;
    const int l     = s >> 6;
    const int chunk = s & 63;
    const int t     = threadIdx.x;

    const int sz = CG_SIZE[l];
    const unsigned* __restrict__ src = compact + CG_OFF[l];
    const int n4 = (sz + 4) >> 2;                  // rounds up so sgrid[sz] is staged
    for (int i = t; i < n4; i += 1024) {
        const uint4v v = *reinterpret_cast<const uint4v*>(src + i * 4);
        *reinterpret_cast<uint4v*>(&sgrid[i * 4]) = v;
    }
    __syncthreads();

    const float r  = RES_C[l];
    const int   r1 = CG_R1[l];
    const int   p0 = chunk * 4096 + t;

    float cx[4], cy[4], cz[4];
    #pragma unroll
    for (int k = 0; k < 4; ++k) {
        const int p = p0 + k * 1024;
        cx[k] = coords[p * 3 + 0];
        cy[k] = coords[p * 3 + 1];
        cz[k] = coords[p * 3 + 2];
    }

    #pragma unroll
    for (int k = 0; k < 4; ++k) {
        const int p = p0 + k * 1024;
        const float sx = cx[k] * r, sy = cy[k] * r, szf = cz[k] * r;
        const float fx = floorf(sx), fy = floorf(sy), fz = floorf(szf);
        const float gx = ceilf(sx),  gy = ceilf(sy),  gz = ceilf(szf);
        const int ixf = (int)fx, iyf = (int)fy, izf = (int)fz;
        const int ixg = (int)gx, iyg = (int)gy;

        const float wxf = gx - sx, wxc = sx - fx;
        const float uy = gy - sy, ty = sy - fy;
        const float uz = gz - szf, tz = szf - fz;

        const int bf = ixf * r1, bg = ixg * r1;
        const int i0 = (bf + iyf) * r1 + izf;      // (x_f, y_f, z_f) / +1 = z_g
        const int i1 = (bf + iyg) * r1 + izf;      // (x_f, y_g, *)
        const int i2 = (bg + iyf) * r1 + izf;      // (x_g, y_f, *)
        const int i3 = (bg + iyg) * r1 + izf;      // (x_g, y_g, *)

        const half2v c0 = __builtin_bit_cast(half2v, sgrid[i0]);
        const half2v c1 = __builtin_bit_cast(half2v, sgrid[i0 + 1]);
        const half2v c2 = __builtin_bit_cast(half2v, sgrid[i1]);
        const half2v c3 = __builtin_bit_cast(half2v, sgrid[i1 + 1]);
        const half2v c4 = __builtin_bit_cast(half2v, sgrid[i2]);
        const half2v c5 = __builtin_bit_cast(half2v, sgrid[i2 + 1]);
        const half2v c6 = __builtin_bit_cast(half2v, sgrid[i3]);
        const half2v c7 = __builtin_bit_cast(half2v, sgrid[i3 + 1]);

        const float w0 = wxf * uy * uz, w1 = wxf * uy * tz;
        const float w2 = wxf * ty * uz, w3 = wxf * ty * tz;
        const float w4 = wxc * uy * uz, w5 = wxc * uy * tz;
        const float w6 = wxc * ty * uz, w7 = wxc * ty * tz;

        float e0f = w0 * (float)c0[0] + w1 * (float)c1[0] + w2 * (float)c2[0] + w3 * (float)c3[0];
        float e1f = w0 * (float)c0[1] + w1 * (float)c1[1] + w2 * (float)c2[1] + w3 * (float)c3[1];
        float e0c = w4 * (float)c4[0] + w5 * (float)c5[0] + w6 * (float)c6[0] + w7 * (float)c7[0];
        float e1c = w4 * (float)c4[1] + w5 * (float)c5[1] + w6 * (float)c6[1] + w7 * (float)c7[1];
        const float e0 = e0f + e0c;
        const float e1 = e1f + e1c;

        half2v h; h[0] = (half_t)(e0 * SCALE); h[1] = (half_t)(e1 * SCALE);
        *reinterpret_cast<half2v*>(&encT[((size_t)l * npts + p) * 2]) = h;
    }
}

// ---------------- In-register layer transition (proven correct: absmax unchanged R1-R7) ----------------
__device__ __forceinline__ unsigned pack_relu2(float x, float y) {
    half2v h;
    h[0] = (half_t)fmaxf(x, 0.f);
    h[1] = (half_t)fmaxf(y, 0.f);
    return __builtin_bit_cast(unsigned, h);
}

__device__ __forceinline__ void xpose_relu(const float4v acc[4], int lane,
                                           half8& b0, half8& b1) {
    unsigned X[4], Y[4];
    X[0] = pack_relu2(acc[0][0], acc[0][1]);
    X[1] = pack_relu2(acc[0][2], acc[0][3]);
    X[2] = pack_relu2(acc[2][0], acc[2][1]);
    X[3] = pack_relu2(acc[2][2], acc[2][3]);
    Y[0] = pack_relu2(acc[1][0], acc[1][1]);
    Y[1] = pack_relu2(acc[1][2], acc[1][3]);
    Y[2] = pack_relu2(acc[3][0], acc[3][1]);
    Y[3] = pack_relu2(acc[3][2], acc[3][3]);
    const bool lo = (lane & 32) == 0;
    const bool ev = (lane & 16) == 0;
    uint4v u0, u1;
    #pragma unroll
    for (int j = 0; j < 4; ++j) {
        const unsigned s1 = lo ? Y[j] : X[j];
        const unsigned t1 = __shfl_xor(s1, 32, 64);
        const unsigned A1 = lo ? X[j] : t1;
        const unsigned B1 = lo ? t1 : Y[j];
        const unsigned s2 = ev ? B1 : A1;
        const unsigned t2 = __shfl_xor(s2, 16, 64);
        const unsigned a2 = ev ? A1 : t2;
        const unsigned b2 = ev ? t2 : B1;
        if (j < 2) { u0[j] = a2; u0[2 + j] = b2; }
        else       { u1[j - 2] = a2; u1[j] = b2; }
    }
    b0 = __builtin_bit_cast(half8, u0);
    b1 = __builtin_bit_cast(half8, u1);
}

// ---------------- Kernel B: register-transpose MLP (measured ~11us; unchanged) ----------------
__global__ __launch_bounds__(256, 3) void nerf_mlp7(
    const half_t* __restrict__ encT,
    const half8* __restrict__ frags,
    const float* __restrict__ b_in, const float* __restrict__ b_h0,
    const float* __restrict__ b_h1, const float* __restrict__ b_out,
    float* __restrict__ out, int npts)
{
    const int t    = threadIdx.x;
    const int lane = t & 63;
    const int wv   = t >> 6;
    const int m    = lane & 15;
    const int quad = lane >> 4;
    const size_t pbase = (size_t)blockIdx.x * 256 + (size_t)wv * 64;

    half8 be[4];
    #pragma unroll
    for (int T = 0; T < 4; ++T) {
        #pragma unroll
        for (int d = 0; d < 4; ++d) {
            const int L = quad * 4 + d;
            const half2v v = *reinterpret_cast<const half2v*>(
                &encT[((size_t)L * npts + pbase + T * 16 + m) * 2]);
            be[T][d * 2 + 0] = v[0];
            be[T][d * 2 + 1] = v[1];
        }
    }

    half8 bf0[4], bf1[4];

    // ---- layer 1: 32 -> 64 ----
    {
        half8 w[4];
        #pragma unroll
        for (int f = 0; f < 4; ++f) w[f] = frags[(0 + f) * 64 + lane];
        float4v cin[4];
        #pragma unroll
        for (int mt = 0; mt < 4; ++mt)
            cin[mt] = (*reinterpret_cast<const float4v*>(b_in + mt * 16 + quad * 4)) * SCALE;
        #pragma unroll
        for (int T = 0; T < 4; ++T) {
            float4v acc[4];
            #pragma unroll
            for (int mt = 0; mt < 4; ++mt) acc[mt] = mfma16(w[mt], be[T], cin[mt]);
            xpose_relu(acc, lane, bf0[T], bf1[T]);
        }
    }
    // ---- layer 2: 64 -> 64 ----
    {
        half8 w[8];
        #pragma unroll
        for (int f = 0; f < 8; ++f) w[f] = frags[(4 + f) * 64 + lane];
        float4v cin[4];
        #pragma unroll
        for (int mt = 0; mt < 4; ++mt)
            cin[mt] = (*reinterpret_cast<const float4v*>(b_h0 + mt * 16 + quad * 4)) * SCALE;
        #pragma unroll
        for (int T = 0; T < 4; ++T) {
            float4v acc[4];
            #pragma unroll
            for (int mt = 0; mt < 4; ++mt) {
                acc[mt] = mfma16(w[mt * 2 + 0], bf0[T], cin[mt]);
                acc[mt] = mfma16(w[mt * 2 + 1], bf1[T], acc[mt]);
            }
            xpose_relu(acc, lane, bf0[T], bf1[T]);
        }
    }
    // ---- layer 3: 64 -> 64 ----
    {
        half8 w[8];
        #pragma unroll
        for (int f = 0; f < 8; ++f) w[f] = frags[(12 + f) * 64 + lane];
        float4v cin[4];
        #pragma unroll
        for (int mt = 0; mt < 4; ++mt)
            cin[mt] = (*reinterpret_cast<const float4v*>(b_h1 + mt * 16 + quad * 4)) * SCALE;
        #pragma unroll
        for (int T = 0; T < 4; ++T) {
            float4v acc[4];
            #pragma unroll
            for (int mt = 0; mt < 4; ++mt) {
                acc[mt] = mfma16(w[mt * 2 + 0], bf0[T], cin[mt]);
                acc[mt] = mfma16(w[mt * 2 + 1], bf1[T], acc[mt]);
            }
            xpose_relu(acc, lane, bf0[T], bf1[T]);
        }
    }
    // ---- layer 4: 64 -> 16, coalesced float4 store ----
    {
        const half8 w0 = frags[20 * 64 + lane];
        const half8 w1 = frags[21 * 64 + lane];
        const float4v b4 = *reinterpret_cast<const float4v*>(b_out + quad * 4);
        const float4v zero = {0.f, 0.f, 0.f, 0.f};
        #pragma unroll
        for (int T = 0; T < 4; ++T) {
            float4v acc = mfma16(w0, bf0[T], zero);
            acc         = mfma16(w1, bf1[T], acc);
            float4v res;
            #pragma unroll
            for (int r = 0; r < 4; ++r) res[r] = fmaf(acc[r], INV_SCALE, b4[r]);
            *reinterpret_cast<float4v*>(out + (pbase + T * 16 + m) * 16 + quad * 4) = res;
        }
    }
}

// ---------------- Fallback: fused kernel (used only if ws too small; unchanged) ----------------
__global__ __launch_bounds__(256, 2) void nerf_fused(
    const float* __restrict__ coords,
    const float2* __restrict__ tab,
    const float* __restrict__ w_in, const float* __restrict__ b_in,
    const float* __restrict__ w_h0, const float* __restrict__ b_h0,
    const float* __restrict__ w_h1, const float* __restrict__ b_h1,
    const float* __restrict__ w_out, const float* __restrict__ b_out,
    float* __restrict__ out, int npts)
{
    __shared__ half_t encS[256 * 40];
    __shared__ half_t actS[4][2][32 * 64];

    const int t    = threadIdx.x;
    const int lane = t & 63;
    const int wv   = t >> 6;
    const int m    = lane & 15;
    const int quad = lane >> 4;
    const int pt = blockIdx.x * 256 + t;

    {
        const float cx = coords[pt * 3 + 0];
        const float cy = coords[pt * 3 + 1];
        const float cz = coords[pt * 3 + 2];
        float enc[32];
        #pragma unroll
        for (int l = 0; l < NLVL; ++l) {
            const float r = RES_C[l];
            const float sx = cx * r, sy = cy * r, sz = cz * r;
            const float fx = floorf(sx), fy = floorf(sy), fz = floorf(sz);
            const float gx = ceilf(sx),  gy = ceilf(sy),  gz = ceilf(sz);
            const unsigned hfx = (unsigned)(int)fx;
            const unsigned hgx = (unsigned)(int)gx;
            const unsigned hfy = (unsigned)(int)fy * 2654435761u;
            const unsigned hgy = (unsigned)(int)gy * 2654435761u;
            const unsigned hfz = (unsigned)(int)fz * 805459861u;
            const unsigned hgz = (unsigned)(int)gz * 805459861u;
            const float tx = sx - fx, ty = sy - fy, tz = sz - fz;
            const float ux = gx - sx, uy = gy - sy, uz = gz - sz;
            const unsigned lbase = ((unsigned)l) << LOGT;
            float e0 = 0.f, e1 = 0.f;
            #pragma unroll
            for (int o = 0; o < 8; ++o) {
                const unsigned h = ((o & 4) ? hgx : hfx)
                                 ^ ((o & 2) ? hgy : hfy)
                                 ^ ((o & 1) ? hgz : hfz);
                const unsigned idx = h & TMASK;
                const float w = (((o & 4) ? tx : ux)
                              *  ((o & 2) ? ty : uy))
                              *  ((o & 1) ? tz : uz);
                const float2 fv = tab[lbase + idx];
                e0 = fmaf(w, fv.x, e0);
                e1 = fmaf(w, fv.y, e1);
            }
            enc[2 * l + 0] = e0;
            enc[2 * l + 1] = e1;
        }
        #pragma unroll
        for (int c = 0; c < 4; ++c) {
            half8 h8;
            #pragma unroll
            for (int j = 0; j < 8; ++j) h8[j] = (half_t)(enc[c * 8 + j] * SCALE);
            *reinterpret_cast<half8*>(&encS[t * 40 + c * 8]) = h8;
        }
    }

    auto loadA = [&](const float* __restrict__ W, int ncol, int row, int col) -> half8 {
        const float* p = W + row * ncol + col;
        const float4v lo = *reinterpret_cast<const float4v*>(p);
        const float4v hi = *reinterpret_cast<const float4v*>(p + 4);
        half8 r;
        r[0] = (half_t)lo[0]; r[1] = (half_t)lo[1]; r[2] = (half_t)lo[2]; r[3] = (half_t)lo[3];
        r[4] = (half_t)hi[0]; r[5] = (half_t)hi[1]; r[6] = (half_t)hi[2]; r[7] = (half_t)hi[3];
        return r;
    };

    half8 aL1[4], aL2[8], aL3[8], aL4[2];
    #pragma unroll
    for (int mt = 0; mt < 4; ++mt) aL1[mt] = loadA(w_in, 32, mt * 16 + m, quad * 8);
    #pragma unroll
    for (int mt = 0; mt < 4; ++mt) {
        aL2[mt * 2 + 0] = loadA(w_h0, 64, mt * 16 + m, 0 * 32 + quad * 8);
        aL2[mt * 2 + 1] = loadA(w_h0, 64, mt * 16 + m, 1 * 32 + quad * 8);
        aL3[mt * 2 + 0] = loadA(w_h1, 64, mt * 16 + m, 0 * 32 + quad * 8);
        aL3[mt * 2 + 1] = loadA(w_h1, 64, mt * 16 + m, 1 * 32 + quad * 8);
    }
    aL4[0] = loadA(w_out, 64, m, 0 * 32 + quad * 8);
    aL4[1] = loadA(w_out, 64, m, 1 * 32 + quad * 8);

    float4v bL1[4], bL2[4], bL3[4], bL4;
    #pragma unroll
    for (int mt = 0; mt < 4; ++mt) {
        bL1[mt] = *reinterpret_cast<const float4v*>(b_in + mt * 16 + quad * 4);
        bL2[mt] = *reinterpret_cast<const float4v*>(b_h0 + mt * 16 + quad * 4);
        bL3[mt] = *reinterpret_cast<const float4v*>(b_h1 + mt * 16 + quad * 4);
    }
    bL4 = *reinterpret_cast<const float4v*>(b_out + quad * 4);

    half_t* const ping = &actS[wv][0][0];
    half_t* const pong = &actS[wv][1][0];
    const float4v zero = {0.f, 0.f, 0.f, 0.f};

    auto storeTile = [&](half_t* buf, int lp, int mt, float4v acc, float4v bias) {
        half4 h4;
        #pragma unroll
        for (int r = 0; r < 4; ++r)
            h4[r] = (half_t)fmaxf(fmaf(bias[r], SCALE, acc[r]), 0.f);
        const int c16  = mt * 2 + (quad >> 1);
        const int phys = c16 ^ (lp & 7);
        *reinterpret_cast<half4*>(&buf[lp * 64 + phys * 8 + (quad & 1) * 4]) = h4;
    };
    auto loadB = [&](half_t* buf, int lp, int h) -> half8 {
        const int phys = (h * 4 + quad) ^ (lp & 7);
        return *reinterpret_cast<const half8*>(&buf[lp * 64 + phys * 8]);
    };

    for (int g = 0; g < 2; ++g) {
        #pragma unroll
        for (int nt = 0; nt < 2; ++nt) {
            const int lp   = nt * 16 + m;
            const int prow = wv * 64 + g * 32 + lp;
            const half8 bfr = *reinterpret_cast<const half8*>(&encS[prow * 40 + quad * 8]);
            #pragma unroll
            for (int mt = 0; mt < 4; ++mt) {
                float4v acc = mfma16(aL1[mt], bfr, zero);
                storeTile(ping, lp, mt, acc, bL1[mt]);
            }
            {
                const half8 p0 = loadB(ping, lp, 0);
                const half8 p1 = loadB(ping, lp, 1);
                #pragma unroll
                for (int mt = 0; mt < 4; ++mt) {
                    float4v acc = mfma16(aL2[mt * 2 + 0], p0, zero);
                    acc         = mfma16(aL2[mt * 2 + 1], p1, acc);
                    storeTile(pong, lp, mt, acc, bL2[mt]);
                }
            }
            {
                const half8 p0 = loadB(pong, lp, 0);
                const half8 p1 = loadB(pong, lp, 1);
                #pragma unroll
                for (int mt = 0; mt < 4; ++mt) {
                    float4v acc = mfma16(aL3[mt * 2 + 0], p0, zero);
                    acc         = mfma16(aL3[mt * 2 + 1], p1, acc);
                    storeTile(ping, lp, mt, acc, bL3[mt]);
                }
            }
            {
                const half8 p0 = loadB(ping, lp, 0);
                const half8 p1 = loadB(ping, lp, 1);
                float4v acc = mfma16(aL4[0], p0, zero);
                acc         = mfma16(aL4[1], p1, acc);
                float4v res;
                #pragma unroll
                for (int r = 0; r < 4; ++r)
                    res[r] = fmaf(acc[r], INV_SCALE, bL4[r]);
                const size_t ptg = (size_t)blockIdx.x * 256 + (size_t)wv * 64 + g * 32 + lp;
                *reinterpret_cast<float4v*>(out + ptg * 16 + quad * 4) = res;
            }
        }
    }
}

extern "C" void kernel_launch(void* const* d_in, const int* in_sizes, int n_in,
                              void* d_out, int out_size, void* d_ws, size_t ws_size,
                              hipStream_t stream) {
    const float*  coords = (const float*)d_in[0];
    const float2* tables = (const float2*)d_in[1];
    const float*  w_in   = (const float*)d_in[2];
    const float*  b_in   = (const float*)d_in[3];
    const float*  w_h0   = (const float*)d_in[4];
    const float*  b_h0   = (const float*)d_in[5];
    const float*  w_h1   = (const float*)d_in[6];
    const float*  b_h1   = (const float*)d_in[7];
    const float*  w_out  = (const float*)d_in[8];
    const float*  b_out  = (const float*)d_in[9];
    float* out = (float*)d_out;

    const int npts = in_sizes[0] / 3;      // 262144
    const size_t encBytes     = (size_t)npts * 32 * sizeof(half_t);     // 16.8 MB
    const size_t fragBytes    = (size_t)NFRAG * 64 * sizeof(half8);     // 22.5 KB
    const size_t compactBytes = (size_t)CG_TOTAL_PAD * sizeof(unsigned);// 270.8 KB

    // staged-grid geometry (64 chunks of 4096) requires npts == 262144 exactly
    if (ws_size >= encBytes + fragBytes + compactBytes && npts == 262144) {
        half_t*   encT    = (half_t*)d_ws;
        half8*    frags   = (half8*)((char*)d_ws + encBytes);
        unsigned* compact = (unsigned*)((char*)d_ws + encBytes + fragBytes);
        const int bpl = npts >> 8;
        // 12 hashed levels (phase A: 8*bpl, phase B: 4*bpl) + 22 wprep + 265 compact tails
        nerf_encode_h12<<<12 * bpl + NFRAG + CG_BLOCKS, 256, 0, stream>>>(
            coords, tables, w_in, w_h0, w_h1, w_out, frags, compact, encT, npts);
        // levels 0..3 from LDS-staged compact grids (4 levels x 64 chunks, 1024 thr)
        nerf_encode_stage<<<4 * 64, 1024, 0, stream>>>(coords, compact, encT, npts);
        nerf_mlp7<<<npts / 256, 256, 0, stream>>>(encT, frags,
                                                  b_in, b_h0, b_h1, b_out,
                                                  out, npts);
    } else {
        nerf_fused<<<npts / 256, 256, 0, stream>>>(coords, tables,
                                                   w_in, b_in, w_h0, b_h0,
                                                   w_h1, b_h1, w_out, b_out,
                                                   out, npts);
    }
}